// Round 5
// baseline (433.426 us; speedup 1.0000x reference)
//
#include <hip/hip_runtime.h>
#include <math.h>

// Problem constants (match reference)
#define B 32
#define C 4
#define P (360*640)        // 230400 pixels per batch
#define L 5                // MAX_LANES
#define DELTA_V 1.0f
#define DELTA_D 6.0f

#define NV 25              // per-block partials: 20 sums (5 lanes x 4 ch) + 5 counts
#define BLK1 30            // contiguous chunks per batch
#define NBLK (B*BLK1)      // 960 streaming blocks
#define G4 (P/4)           // 57600 int4/float4 groups per batch
#define CHUNK_G (G4/BLK1)  // 1920 groups per chunk
#define ITERS ((CHUNK_G + 255)/256)   // 8 stages; stage 7 is half-wave (1920 = 7.5*256)

__device__ __forceinline__ float waveReduce(float v) {
#pragma unroll
    for (int off = 32; off; off >>= 1) v += __shfl_down(v, off, 64);
    return v;
}

// One pipeline stage: 5 x 16B loads (80 B/lane) kept in distinct registers.
struct Stage { int4 t; float4 a0, a1, a2, a3; };

// ---------------------------------------------------------------------------
// Kernel 1: per-(batch,lane) segment sums + counts, deterministic block partials
// Explicit 3-deep software pipeline: loads for stage i+2 are issued before
// stage i is consumed -> ~10 outstanding 16B loads per wave.
// (round-1 build: VGPR=32 forced 1 load in flight -> 2.2 TB/s latency-bound;
//  round-4 showed more waves do NOT fix it, so we buy per-wave MLP instead.)
// ---------------------------------------------------------------------------
__global__ __launch_bounds__(256, 4) void seg_sums_k(const int* __restrict__ tgt,
                                                     const float* __restrict__ emb,
                                                     float* __restrict__ part1) {
    const int b   = blockIdx.y;
    const int tid = threadIdx.x;
    const int gbase = blockIdx.x * CHUNK_G;

    const int4*   t4 = (const int4*)(tgt + (size_t)b * P);
    const float4* e0 = (const float4*)(emb + (size_t)(b*C + 0) * P);
    const float4* e1 = (const float4*)(emb + (size_t)(b*C + 1) * P);
    const float4* e2 = (const float4*)(emb + (size_t)(b*C + 2) * P);
    const float4* e3 = (const float4*)(emb + (size_t)(b*C + 3) * P);

    float s[L][C], cn[L];
#pragma unroll
    for (int l = 0; l < L; ++l) { cn[l]=0.f; s[l][0]=s[l][1]=s[l][2]=s[l][3]=0.f; }

    auto load_full = [&](int it) {
        Stage st;
        const int g = gbase + it*256 + tid;
        st.t = t4[g];
        st.a0 = e0[g]; st.a1 = e1[g]; st.a2 = e2[g]; st.a3 = e3[g];
        return st;
    };
    auto load_tail = [&](int it) {
        Stage st;
        const int off = it*256 + tid;
        const bool v  = off < CHUNK_G;
        const int g   = gbase + (v ? off : 0);
        st.t = t4[g];
        st.a0 = e0[g]; st.a1 = e1[g]; st.a2 = e2[g]; st.a3 = e3[g];
        if (!v) { st.t.x = 0; st.t.y = 0; st.t.z = 0; st.t.w = 0; }  // label 0 -> no lane
        return st;
    };

    auto proc1 = [&](int tt, float x0, float x1, float x2, float x3) {
#pragma unroll
        for (int l = 0; l < L; ++l) {
            float m = (tt == l + 1) ? 1.0f : 0.0f;
            cn[l] += m;
            s[l][0] = fmaf(m, x0, s[l][0]);
            s[l][1] = fmaf(m, x1, s[l][1]);
            s[l][2] = fmaf(m, x2, s[l][2]);
            s[l][3] = fmaf(m, x3, s[l][3]);
        }
    };
    auto procS = [&](const Stage& st) {
        proc1(st.t.x, st.a0.x, st.a1.x, st.a2.x, st.a3.x);
        proc1(st.t.y, st.a0.y, st.a1.y, st.a2.y, st.a3.y);
        proc1(st.t.z, st.a0.z, st.a1.z, st.a2.z, st.a3.z);
        proc1(st.t.w, st.a0.w, st.a1.w, st.a2.w, st.a3.w);
    };

    Stage sA = load_full(0);
    Stage sB = load_full(1);
#pragma unroll
    for (int it = 0; it < ITERS - 3; ++it) {       // loads stages 2..ITERS-2
        Stage sC = load_full(it + 2);
        procS(sA);
        sA = sB; sB = sC;
    }
    Stage sC = load_tail(ITERS - 1);               // masked half-wave stage
    procS(sA);
    procS(sB);
    procS(sC);

    // pack 25 values, wave-reduce each, then cross-wave via LDS
    float vals[NV];
#pragma unroll
    for (int l = 0; l < L; ++l) {
#pragma unroll
        for (int c = 0; c < C; ++c) vals[l*4 + c] = s[l][c];
        vals[20 + l] = cn[l];
    }
    __shared__ float red[4][NV];
    const int lane = tid & 63, wave = tid >> 6;
#pragma unroll
    for (int k = 0; k < NV; ++k) {
        float r = waveReduce(vals[k]);
        if (lane == 0) red[wave][k] = r;
    }
    __syncthreads();
    if (tid < NV) {
        float r = red[0][tid] + red[1][tid] + red[2][tid] + red[3][tid];
        part1[(size_t)(b * BLK1 + blockIdx.x) * NV + tid] = r;
    }
}

// ---------------------------------------------------------------------------
// Kernel 2: wave-per-segment partial reduction -> means / valid / count
// 160 segments, one wave each; lanes 0..BLK1-1 = chunk index
// ---------------------------------------------------------------------------
__global__ __launch_bounds__(256) void means_k(const float* __restrict__ part1,
                                               float* __restrict__ means,
                                               float* __restrict__ validf,
                                               float* __restrict__ cntv) {
    const int seg  = (blockIdx.x * 256 + threadIdx.x) >> 6;   // global wave id
    const int lane = threadIdx.x & 63;
    if (seg >= B * L) return;
    const int b = seg / L, l = seg % L;

    float v0=0.f, v1=0.f, v2=0.f, v3=0.f, vc=0.f;
    if (lane < BLK1) {
        const float* p = part1 + (size_t)(b * BLK1 + lane) * NV;
        v0 = p[l*4+0]; v1 = p[l*4+1]; v2 = p[l*4+2]; v3 = p[l*4+3]; vc = p[20+l];
    }
    v0 = waveReduce(v0); v1 = waveReduce(v1); v2 = waveReduce(v2);
    v3 = waveReduce(v3); vc = waveReduce(vc);
    if (lane == 0) {
        const float inv = 1.0f / fmaxf(vc, 1.0f);
        const bool  v   = vc > 1.5f;    // integer count > 1
        means[seg*4+0] = v0 * inv;
        means[seg*4+1] = v1 * inv;
        means[seg*4+2] = v2 * inv;
        means[seg*4+3] = v3 * inv;
        validf[seg] = v ? 1.f : 0.f;
        cntv[seg]   = v ? vc  : 0.f;
    }
}

// ---------------------------------------------------------------------------
// Kernel 3: pull (variance) loss — same 3-deep pipeline as kernel 1
// ---------------------------------------------------------------------------
__global__ __launch_bounds__(256, 4) void pull_k(const int* __restrict__ tgt,
                                                 const float* __restrict__ emb,
                                                 const float* __restrict__ means,
                                                 const float* __restrict__ validf,
                                                 float* __restrict__ part3) {
    __shared__ float4 lmean[L + 1];   // label 0 -> zero mean
    __shared__ float  lvalid[L + 1];  // label 0 -> invalid
    __shared__ float  lred[4];
    const int b   = blockIdx.y;
    const int tid = threadIdx.x;
    const int gbase = blockIdx.x * CHUNK_G;

    if (tid == 0) { lmean[0] = make_float4(0.f, 0.f, 0.f, 0.f); lvalid[0] = 0.f; }
    else if (tid <= L) {
        lmean[tid]  = *(const float4*)(means + ((size_t)b*L + (tid-1)) * C);
        lvalid[tid] = validf[b*L + (tid-1)];
    }
    __syncthreads();

    const int4*   t4 = (const int4*)(tgt + (size_t)b * P);
    const float4* e0 = (const float4*)(emb + (size_t)(b*C + 0) * P);
    const float4* e1 = (const float4*)(emb + (size_t)(b*C + 1) * P);
    const float4* e2 = (const float4*)(emb + (size_t)(b*C + 2) * P);
    const float4* e3 = (const float4*)(emb + (size_t)(b*C + 3) * P);

    auto load_full = [&](int it) {
        Stage st;
        const int g = gbase + it*256 + tid;
        st.t = t4[g];
        st.a0 = e0[g]; st.a1 = e1[g]; st.a2 = e2[g]; st.a3 = e3[g];
        return st;
    };
    auto load_tail = [&](int it) {
        Stage st;
        const int off = it*256 + tid;
        const bool v  = off < CHUNK_G;
        const int g   = gbase + (v ? off : 0);
        st.t = t4[g];
        st.a0 = e0[g]; st.a1 = e1[g]; st.a2 = e2[g]; st.a3 = e3[g];
        if (!v) { st.t.x = 0; st.t.y = 0; st.t.z = 0; st.t.w = 0; }  // lvalid[0]=0 -> no contrib
        return st;
    };

    float acc = 0.f;
    auto proc1 = [&](int tt, float x0, float x1, float x2, float x3) {
        float4 m = lmean[tt];
        float d0 = x0 - m.x, d1 = x1 - m.y, d2 = x2 - m.z, d3 = x3 - m.w;
        float sq   = d0*d0 + d1*d1 + d2*d2 + d3*d3;
        float dist = sqrtf(fmaxf(sq, 1e-12f));
        float h    = fmaxf(dist - DELTA_V, 0.f);
        acc = fmaf(lvalid[tt] * h, h, acc);
    };
    auto procS = [&](const Stage& st) {
        proc1(st.t.x, st.a0.x, st.a1.x, st.a2.x, st.a3.x);
        proc1(st.t.y, st.a0.y, st.a1.y, st.a2.y, st.a3.y);
        proc1(st.t.z, st.a0.z, st.a1.z, st.a2.z, st.a3.z);
        proc1(st.t.w, st.a0.w, st.a1.w, st.a2.w, st.a3.w);
    };

    Stage sA = load_full(0);
    Stage sB = load_full(1);
#pragma unroll
    for (int it = 0; it < ITERS - 3; ++it) {
        Stage sC = load_full(it + 2);
        procS(sA);
        sA = sB; sB = sC;
    }
    Stage sC = load_tail(ITERS - 1);
    procS(sA);
    procS(sB);
    procS(sC);

    float r = waveReduce(acc);
    const int lane = tid & 63, wave = tid >> 6;
    if (lane == 0) lred[wave] = r;
    __syncthreads();
    if (tid == 0)
        part3[b * BLK1 + blockIdx.x] = lred[0] + lred[1] + lred[2] + lred[3];
}

// ---------------------------------------------------------------------------
// Kernel 4: final combine — push loss + point_count + pull partial sum
// ---------------------------------------------------------------------------
__global__ __launch_bounds__(256) void finish_k(const float* __restrict__ part3,
                                                const float* __restrict__ means,
                                                const float* __restrict__ validf,
                                                const float* __restrict__ cntv,
                                                float* __restrict__ out) {
    __shared__ float red[4][4];
    const int tid = threadIdx.x;
    const int lane = tid & 63, wave = tid >> 6;

    // push (distance) loss: one thread per batch over the 10 mean pairs
    float vb = 0.f, has = 0.f;
    if (tid < B) {
        const float* mb = means  + tid * L * 4;
        const float* vv = validf + tid * L;
        float ssum = 0.f, np = 0.f;
#pragma unroll
        for (int i = 0; i < L; ++i)
#pragma unroll
            for (int j = i + 1; j < L; ++j) {
                float ok = vv[i] * vv[j];
                float d0 = mb[i*4+0] - mb[j*4+0];
                float d1 = mb[i*4+1] - mb[j*4+1];
                float d2 = mb[i*4+2] - mb[j*4+2];
                float d3 = mb[i*4+3] - mb[j*4+3];
                float psq = d0*d0 + d1*d1 + d2*d2 + d3*d3;
                float pd  = sqrtf(fmaxf(psq, 1e-12f));
                float ph  = fmaxf(DELTA_D - pd, 0.f);
                ssum += ok * ph * ph;
                np   += ok;
            }
        if (np > 0.f) { vb = ssum / np; has = 1.f; }
    }
    float pc = (tid < B*L) ? cntv[tid] : 0.f;
    float ps = 0.f;
    for (int i = tid; i < NBLK; i += 256) ps += part3[i];

    float rvb = waveReduce(vb);
    float rhs = waveReduce(has);
    float rpc = waveReduce(pc);
    float rps = waveReduce(ps);
    if (lane == 0) { red[wave][0]=rvb; red[wave][1]=rhs; red[wave][2]=rpc; red[wave][3]=rps; }
    __syncthreads();
    if (tid == 0) {
        float svb = red[0][0]+red[1][0]+red[2][0]+red[3][0];
        float shs = red[0][1]+red[1][1]+red[2][1]+red[3][1];
        float spc = red[0][2]+red[1][2]+red[2][2]+red[3][2];
        float sps = red[0][3]+red[1][3]+red[2][3]+red[3][3];
        float var = (shs > 0.f) ? svb / shs : 0.f;              // push loss
        float dl  = (spc > 0.f) ? sps / fmaxf(spc, 1.f) : 0.f;  // pull loss
        out[0] = dl + var;
    }
}

// ---------------------------------------------------------------------------
extern "C" void kernel_launch(void* const* d_in, const int* in_sizes, int n_in,
                              void* d_out, int out_size, void* d_ws, size_t ws_size,
                              hipStream_t stream) {
    const int*   tgt = (const int*)d_in[0];    // targets int32 [B,H,W]
    const float* emb = (const float*)d_in[1];  // embedding fp32 [B,C,H,W]

    float* ws     = (float*)d_ws;
    float* part1  = ws;                         // NBLK*NV = 24000 floats
    float* means  = part1 + (size_t)NBLK * NV;  // 640 floats (byte off 96000, 16B-aligned)
    float* validf = means + B*L*C;              // 160 floats
    float* cntv   = validf + B*L;               // 160 floats
    float* part3  = cntv + B*L;                 // NBLK floats
    // total ws use: ~104 KB

    dim3 grid(BLK1, B);                         // 960 blocks
    seg_sums_k<<<grid, 256, 0, stream>>>(tgt, emb, part1);
    means_k<<<(B*L + 3) / 4, 256, 0, stream>>>(part1, means, validf, cntv);  // 160 waves
    pull_k<<<grid, 256, 0, stream>>>(tgt, emb, means, validf, part3);
    finish_k<<<1, 256, 0, stream>>>(part3, means, validf, cntv, (float*)d_out);
}

// Round 6
// 218.577 us; speedup vs baseline: 1.9829x; 1.9829x over previous
//
#include <hip/hip_runtime.h>
#include <math.h>

// Problem constants (match reference)
#define B 32
#define C 4
#define P (360*640)        // 230400 pixels per batch
#define L 5                // MAX_LANES
#define DELTA_V 1.0f
#define DELTA_D 6.0f

#define BLKX 45            // chunks per batch; 225 wave-steps / 45 = 5 iters exactly
#define ITER1 5
#define G4 (P/4)           // 57600 int4/float4 groups per batch (= 225*256)
#define NBLK3 (B*BLKX)     // 1440 pull partials

__device__ __forceinline__ float waveReduce(float v) {
#pragma unroll
    for (int off = 32; off; off >>= 1) v += __shfl_down(v, off, 64);
    return v;
}

// ---------------------------------------------------------------------------
// Kernel 1: channel-split segment sums. Block = (chunk x, channel c, batch b).
// 2 streams (t + one channel plane), 10 accumulators. All 5 iterations' loads
// live in flat register arrays -> 10 independent 16B loads in flight per wave.
// (R1/R4: VGPR=32 + 25 accums -> ~1 load in flight -> 2.2 TB/s wall.
//  R5: struct/lambda pipeline -> scratch spills (WRITE_SIZE 195MB). Flat SSA only.)
// ---------------------------------------------------------------------------
__global__ __launch_bounds__(256, 4) void seg_sums_k(const int* __restrict__ tgt,
                                                     const float* __restrict__ emb,
                                                     float* __restrict__ sums,
                                                     float* __restrict__ cnts) {
    const int x = blockIdx.x, c = blockIdx.y, b = blockIdx.z;
    const int tid = threadIdx.x;

    const int4*   t4 = (const int4*)(tgt + (size_t)b * P);
    const float4* ec = (const float4*)(emb + ((size_t)b * C + c) * P);

    int4   tv[ITER1];
    float4 ev[ITER1];
#pragma unroll
    for (int it = 0; it < ITER1; ++it) {
        const int g = (x + it * BLKX) * 256 + tid;
        tv[it] = t4[g];
        ev[it] = ec[g];
    }

    float s[L], n[L];
#pragma unroll
    for (int l = 0; l < L; ++l) { s[l] = 0.f; n[l] = 0.f; }

    auto acc1 = [&](int tt, float e) {
#pragma unroll
        for (int l = 0; l < L; ++l) {
            float m = (tt == l + 1) ? 1.0f : 0.0f;
            n[l] += m;
            s[l] = fmaf(m, e, s[l]);
        }
    };
#pragma unroll
    for (int it = 0; it < ITER1; ++it) {
        acc1(tv[it].x, ev[it].x);
        acc1(tv[it].y, ev[it].y);
        acc1(tv[it].z, ev[it].z);
        acc1(tv[it].w, ev[it].w);
    }

    // reduce 10 values per block
    float vals[2*L];
#pragma unroll
    for (int l = 0; l < L; ++l) { vals[l] = s[l]; vals[L + l] = n[l]; }

    __shared__ float red[4][2*L];
    const int lane = tid & 63, wave = tid >> 6;
#pragma unroll
    for (int k = 0; k < 2*L; ++k) {
        float r = waveReduce(vals[k]);
        if (lane == 0) red[wave][k] = r;
    }
    __syncthreads();
    if (tid < L) {
        float r = red[0][tid] + red[1][tid] + red[2][tid] + red[3][tid];
        sums[((size_t)(b * BLKX + x) * C + c) * L + tid] = r;
    } else if (c == 0 && tid < 2*L) {
        float r = red[0][tid] + red[1][tid] + red[2][tid] + red[3][tid];
        cnts[(size_t)(b * BLKX + x) * L + (tid - L)] = r;
    }
}

// ---------------------------------------------------------------------------
// Kernel 2: wave per (b,l) segment; lanes 0..BLKX-1 = chunk index
// ---------------------------------------------------------------------------
__global__ __launch_bounds__(256) void means_k(const float* __restrict__ sums,
                                               const float* __restrict__ cnts,
                                               float* __restrict__ means,
                                               float* __restrict__ validf,
                                               float* __restrict__ cntv) {
    const int seg  = (blockIdx.x * 256 + threadIdx.x) >> 6;   // global wave id
    const int lane = threadIdx.x & 63;
    if (seg >= B * L) return;
    const int b = seg / L, l = seg % L;

    float v0=0.f, v1=0.f, v2=0.f, v3=0.f, vc=0.f;
    if (lane < BLKX) {
        const size_t base = (size_t)(b * BLKX + lane) * C * L;
        v0 = sums[base + 0*L + l];
        v1 = sums[base + 1*L + l];
        v2 = sums[base + 2*L + l];
        v3 = sums[base + 3*L + l];
        vc = cnts[(size_t)(b * BLKX + lane) * L + l];
    }
    v0 = waveReduce(v0); v1 = waveReduce(v1); v2 = waveReduce(v2);
    v3 = waveReduce(v3); vc = waveReduce(vc);
    if (lane == 0) {
        const float inv = 1.0f / fmaxf(vc, 1.0f);
        const bool  v   = vc > 1.5f;    // integer count > 1
        means[seg*4+0] = v0 * inv;
        means[seg*4+1] = v1 * inv;
        means[seg*4+2] = v2 * inv;
        means[seg*4+3] = v3 * inv;
        validf[seg] = v ? 1.f : 0.f;
        cntv[seg]   = v ? vc  : 0.f;
    }
}

// ---------------------------------------------------------------------------
// Kernel 3: pull loss. 5 streams, flat depth-2 software pipeline (scalars only,
// fully unrolled rotation -> SSA, no struct copies, no tail).
// ---------------------------------------------------------------------------
__global__ __launch_bounds__(256, 4) void pull_k(const int* __restrict__ tgt,
                                                 const float* __restrict__ emb,
                                                 const float* __restrict__ means,
                                                 const float* __restrict__ validf,
                                                 float* __restrict__ part3) {
    __shared__ float4 lmean[L + 1];   // label 0 -> zero mean
    __shared__ float  lvalid[L + 1];  // label 0 -> invalid
    __shared__ float  lred[4];
    const int x = blockIdx.x, b = blockIdx.y;
    const int tid = threadIdx.x;

    if (tid == 0) { lmean[0] = make_float4(0.f, 0.f, 0.f, 0.f); lvalid[0] = 0.f; }
    else if (tid <= L) {
        lmean[tid]  = *(const float4*)(means + ((size_t)b*L + (tid-1)) * 4);
        lvalid[tid] = validf[b*L + (tid-1)];
    }
    __syncthreads();

    const int4*   t4 = (const int4*)(tgt + (size_t)b * P);
    const float4* e0 = (const float4*)(emb + ((size_t)b*C + 0) * P);
    const float4* e1 = (const float4*)(emb + ((size_t)b*C + 1) * P);
    const float4* e2 = (const float4*)(emb + ((size_t)b*C + 2) * P);
    const float4* e3 = (const float4*)(emb + ((size_t)b*C + 3) * P);

    float acc = 0.f;
    auto proc1 = [&](int tt, float v0, float v1, float v2, float v3) {
        float4 m = lmean[tt];
        float d0 = v0 - m.x, d1 = v1 - m.y, d2 = v2 - m.z, d3 = v3 - m.w;
        float sq   = d0*d0 + d1*d1 + d2*d2 + d3*d3;
        float dist = sqrtf(fmaxf(sq, 1e-12f));
        float h    = fmaxf(dist - DELTA_V, 0.f);
        acc = fmaf(lvalid[tt] * h, h, acc);
    };

    // prologue: stage A = iteration 0
    int g = x * 256 + tid;
    int4   ta = t4[g];
    float4 p0 = e0[g], p1 = e1[g], p2 = e2[g], p3 = e3[g];
#pragma unroll
    for (int it = 0; it < ITER1 - 1; ++it) {
        const int gn = (x + (it + 1) * BLKX) * 256 + tid;
        int4   tb = t4[gn];
        float4 q0 = e0[gn], q1 = e1[gn], q2 = e2[gn], q3 = e3[gn];
        proc1(ta.x, p0.x, p1.x, p2.x, p3.x);
        proc1(ta.y, p0.y, p1.y, p2.y, p3.y);
        proc1(ta.z, p0.z, p1.z, p2.z, p3.z);
        proc1(ta.w, p0.w, p1.w, p2.w, p3.w);
        ta = tb; p0 = q0; p1 = q1; p2 = q2; p3 = q3;   // SSA renames (unrolled)
    }
    proc1(ta.x, p0.x, p1.x, p2.x, p3.x);
    proc1(ta.y, p0.y, p1.y, p2.y, p3.y);
    proc1(ta.z, p0.z, p1.z, p2.z, p3.z);
    proc1(ta.w, p0.w, p1.w, p2.w, p3.w);

    float r = waveReduce(acc);
    const int lane = tid & 63, wave = tid >> 6;
    if (lane == 0) lred[wave] = r;
    __syncthreads();
    if (tid == 0)
        part3[b * BLKX + x] = lred[0] + lred[1] + lred[2] + lred[3];
}

// ---------------------------------------------------------------------------
// Kernel 4: final combine — push loss + point_count + pull partial sum
// ---------------------------------------------------------------------------
__global__ __launch_bounds__(256) void finish_k(const float* __restrict__ part3,
                                                const float* __restrict__ means,
                                                const float* __restrict__ validf,
                                                const float* __restrict__ cntv,
                                                float* __restrict__ out) {
    __shared__ float red[4][4];
    const int tid = threadIdx.x;
    const int lane = tid & 63, wave = tid >> 6;

    float vb = 0.f, has = 0.f;
    if (tid < B) {
        const float* mb = means  + tid * L * 4;
        const float* vv = validf + tid * L;
        float ssum = 0.f, np = 0.f;
#pragma unroll
        for (int i = 0; i < L; ++i)
#pragma unroll
            for (int j = i + 1; j < L; ++j) {
                float ok = vv[i] * vv[j];
                float d0 = mb[i*4+0] - mb[j*4+0];
                float d1 = mb[i*4+1] - mb[j*4+1];
                float d2 = mb[i*4+2] - mb[j*4+2];
                float d3 = mb[i*4+3] - mb[j*4+3];
                float psq = d0*d0 + d1*d1 + d2*d2 + d3*d3;
                float pd  = sqrtf(fmaxf(psq, 1e-12f));
                float ph  = fmaxf(DELTA_D - pd, 0.f);
                ssum += ok * ph * ph;
                np   += ok;
            }
        if (np > 0.f) { vb = ssum / np; has = 1.f; }
    }
    float pc = (tid < B*L) ? cntv[tid] : 0.f;
    float ps = 0.f;
    for (int i = tid; i < NBLK3; i += 256) ps += part3[i];

    float rvb = waveReduce(vb);
    float rhs = waveReduce(has);
    float rpc = waveReduce(pc);
    float rps = waveReduce(ps);
    if (lane == 0) { red[wave][0]=rvb; red[wave][1]=rhs; red[wave][2]=rpc; red[wave][3]=rps; }
    __syncthreads();
    if (tid == 0) {
        float svb = red[0][0]+red[1][0]+red[2][0]+red[3][0];
        float shs = red[0][1]+red[1][1]+red[2][1]+red[3][1];
        float spc = red[0][2]+red[1][2]+red[2][2]+red[3][2];
        float sps = red[0][3]+red[1][3]+red[2][3]+red[3][3];
        float var = (shs > 0.f) ? svb / shs : 0.f;              // push loss
        float dl  = (spc > 0.f) ? sps / fmaxf(spc, 1.f) : 0.f;  // pull loss
        out[0] = dl + var;
    }
}

// ---------------------------------------------------------------------------
extern "C" void kernel_launch(void* const* d_in, const int* in_sizes, int n_in,
                              void* d_out, int out_size, void* d_ws, size_t ws_size,
                              hipStream_t stream) {
    const int*   tgt = (const int*)d_in[0];    // targets int32 [B,H,W]
    const float* emb = (const float*)d_in[1];  // embedding fp32 [B,C,H,W]

    float* ws     = (float*)d_ws;
    float* sums   = ws;                          // B*BLKX*C*L = 28800 floats
    float* cnts   = sums + (size_t)B*BLKX*C*L;   // B*BLKX*L   = 7200
    float* means  = cnts + (size_t)B*BLKX*L;     // 640 (byte off 144000, 16B-aligned)
    float* validf = means + B*L*4;               // 160
    float* cntv   = validf + B*L;                // 160
    float* part3  = cntv + B*L;                  // 1440
    // total ws use: ~154 KB

    seg_sums_k<<<dim3(BLKX, C, B), 256, 0, stream>>>(tgt, emb, sums, cnts);   // 5760 blocks
    means_k<<<(B*L + 3) / 4, 256, 0, stream>>>(sums, cnts, means, validf, cntv); // 160 waves
    pull_k<<<dim3(BLKX, B), 256, 0, stream>>>(tgt, emb, means, validf, part3);   // 1440 blocks
    finish_k<<<1, 256, 0, stream>>>(part3, means, validf, cntv, (float*)d_out);
}